// Round 1
// baseline (110.710 us; speedup 1.0000x reference)
//
#include <hip/hip_runtime.h>
#include <hip/hip_bf16.h>

#define ALPHA 0.2f
#define LREL(x) fmaxf((x), ALPHA * (x))

typedef __attribute__((ext_vector_type(8))) short bf16x8;
typedef __attribute__((ext_vector_type(4))) float f32x4;

// f32 -> bf16 (RNE)
static __device__ __forceinline__ unsigned short f2bf(float x) {
    union { float f; unsigned int u; } c;
    c.f = x;
    unsigned int r = c.u + 0x7FFFu + ((c.u >> 16) & 1u);
    return (unsigned short)(r >> 16);
}

// ---------------- Kernel 1: U = x @ W0[:32] + b0,  V = x @ W0[32:] ----------------
// grid 1024 x 256 ; one thread per (node, k)
__global__ __launch_bounds__(256) void k_uv(
    const float* __restrict__ x, const float* __restrict__ W0, const float* __restrict__ b0,
    float* __restrict__ U, float* __restrict__ V)
{
    int idx = blockIdx.x * 256 + threadIdx.x;  // 0 .. 262143
    int n = idx >> 6;                          // node = b*512 + i
    int k = idx & 63;
    const float* xr = x + n * 32;
    float u = b0[k], v = 0.f;
#pragma unroll
    for (int f = 0; f < 32; ++f) {
        float xv = xr[f];
        u += xv * W0[f * 64 + k];
        v += xv * W0[(32 + f) * 64 + k];
    }
    U[idx] = u;
    V[idx] = v;
}

// ---------------- Kernel 2: edge MLP (layers 1,2) + sum over j ----------------
// grid 512 blocks (b, iblk of 8 i's), 256 threads = 4 waves; wave handles 2 i's.
// Per 16-edge group (1 i x 16 j): GEMM1 A from U+V (lrelu fused), LDS repack, GEMM2, agg.
__global__ __launch_bounds__(256) void k_edge(
    const float* __restrict__ U, const float* __restrict__ V,
    const float* __restrict__ W1, const float* __restrict__ b1,
    const float* __restrict__ W2, const float* __restrict__ b2,
    float* __restrict__ AGG)
{
    __shared__ unsigned short h1buf[4][16 * 68];  // per-wave, stride 68 (writes conflict-free)
    const int tid = threadIdx.x;
    const int w = tid >> 6, l = tid & 63;
    const int lo = l & 15, g = l >> 4;            // A/B frag: row/col = lo, k-chunk = g
    const int bid = blockIdx.x;
    const int b = bid >> 6, iblk = bid & 63;

    // W1/W2 B-fragments: lane holds col n = lo, k = 32*s + 8*g + e
    bf16x8 w1f[2][4], w2f[2][4];
    float b1v[4], b2v[4];
#pragma unroll
    for (int s = 0; s < 2; ++s)
#pragma unroll
        for (int nf = 0; nf < 4; ++nf) {
            union { bf16x8 v; unsigned short s_[8]; } t1, t2;
#pragma unroll
            for (int e = 0; e < 8; ++e) {
                int k = 32 * s + 8 * g + e;
                t1.s_[e] = f2bf(W1[k * 64 + nf * 16 + lo]);
                t2.s_[e] = f2bf(W2[k * 64 + nf * 16 + lo]);
            }
            w1f[s][nf] = t1.v;
            w2f[s][nf] = t2.v;
        }
#pragma unroll
    for (int nf = 0; nf < 4; ++nf) {
        b1v[nf] = b1[nf * 16 + lo];
        b2v[nf] = b2[nf * 16 + lo];
    }

    unsigned short* hb = h1buf[w];

#pragma unroll 1
    for (int ii = 0; ii < 2; ++ii) {
        const int i = iblk * 8 + w * 2 + ii;
        const int nodei = b * 512 + i;
        const float* up = U + nodei * 64 + 8 * g;
        const float4 ua = *(const float4*)(up);
        const float4 ub = *(const float4*)(up + 4);
        const float4 uc = *(const float4*)(up + 32);
        const float4 ud = *(const float4*)(up + 36);
        float agg4[4] = {0.f, 0.f, 0.f, 0.f};

#pragma unroll 1
        for (int jc = 0; jc < 512; jc += 16) {
            // ---- build h0 A-fragments: edge row = lo (j = jc+lo), k = 32s + 8g + e
            const float* vp = V + (b * 512 + jc + lo) * 64 + 8 * g;
            const float4 va = *(const float4*)(vp);
            const float4 vb = *(const float4*)(vp + 4);
            const float4 vc = *(const float4*)(vp + 32);
            const float4 vd = *(const float4*)(vp + 36);
            union { bf16x8 v; unsigned short s_[8]; } A0, A1;
            {
                float t;
                t = ua.x + va.x; A0.s_[0] = f2bf(LREL(t));
                t = ua.y + va.y; A0.s_[1] = f2bf(LREL(t));
                t = ua.z + va.z; A0.s_[2] = f2bf(LREL(t));
                t = ua.w + va.w; A0.s_[3] = f2bf(LREL(t));
                t = ub.x + vb.x; A0.s_[4] = f2bf(LREL(t));
                t = ub.y + vb.y; A0.s_[5] = f2bf(LREL(t));
                t = ub.z + vb.z; A0.s_[6] = f2bf(LREL(t));
                t = ub.w + vb.w; A0.s_[7] = f2bf(LREL(t));
                t = uc.x + vc.x; A1.s_[0] = f2bf(LREL(t));
                t = uc.y + vc.y; A1.s_[1] = f2bf(LREL(t));
                t = uc.z + vc.z; A1.s_[2] = f2bf(LREL(t));
                t = uc.w + vc.w; A1.s_[3] = f2bf(LREL(t));
                t = ud.x + vd.x; A1.s_[4] = f2bf(LREL(t));
                t = ud.y + vd.y; A1.s_[5] = f2bf(LREL(t));
                t = ud.z + vd.z; A1.s_[6] = f2bf(LREL(t));
                t = ud.w + vd.w; A1.s_[7] = f2bf(LREL(t));
            }

            // ---- GEMM1: D1[edge][feat1] = h0 @ W1
            f32x4 acc1[4];
#pragma unroll
            for (int nf = 0; nf < 4; ++nf) { f32x4 z = {0.f, 0.f, 0.f, 0.f}; acc1[nf] = z; }
#pragma unroll
            for (int nf = 0; nf < 4; ++nf)
                acc1[nf] = __builtin_amdgcn_mfma_f32_16x16x32_bf16(A0.v, w1f[0][nf], acc1[nf], 0, 0, 0);
#pragma unroll
            for (int nf = 0; nf < 4; ++nf)
                acc1[nf] = __builtin_amdgcn_mfma_f32_16x16x32_bf16(A1.v, w1f[1][nf], acc1[nf], 0, 0, 0);

            // ---- bias + lrelu + repack via per-wave LDS: D layout row=4g+r (edge), col=16nf+lo
#pragma unroll
            for (int nf = 0; nf < 4; ++nf)
#pragma unroll
                for (int r = 0; r < 4; ++r) {
                    float y = acc1[nf][r] + b1v[nf];
                    hb[(4 * g + r) * 68 + nf * 16 + lo] = f2bf(LREL(y));
                }
            asm volatile("s_waitcnt lgkmcnt(0)" ::: "memory");

            // ---- read back as A-fragments: edge = lo, k = 32s + 8g + e
            bf16x8 a1[2];
#pragma unroll
            for (int s = 0; s < 2; ++s) {
                const uint2* p = (const uint2*)(hb + lo * 68 + 32 * s + 8 * g);  // 8B aligned
                union { bf16x8 v; uint2 q[2]; } t;
                t.q[0] = p[0];
                t.q[1] = p[1];
                a1[s] = t.v;
            }

            // ---- GEMM2: D2[edge][feat2] = h1 @ W2
            f32x4 acc2[4];
#pragma unroll
            for (int nf = 0; nf < 4; ++nf) { f32x4 z = {0.f, 0.f, 0.f, 0.f}; acc2[nf] = z; }
#pragma unroll
            for (int nf = 0; nf < 4; ++nf)
                acc2[nf] = __builtin_amdgcn_mfma_f32_16x16x32_bf16(a1[0], w2f[0][nf], acc2[nf], 0, 0, 0);
#pragma unroll
            for (int nf = 0; nf < 4; ++nf)
                acc2[nf] = __builtin_amdgcn_mfma_f32_16x16x32_bf16(a1[1], w2f[1][nf], acc2[nf], 0, 0, 0);

            // ---- bias + lrelu + accumulate sum over the 4 edge-rows this lane holds
#pragma unroll
            for (int nf = 0; nf < 4; ++nf)
#pragma unroll
                for (int r = 0; r < 4; ++r) {
                    float y = acc2[nf][r] + b2v[nf];
                    agg4[nf] += LREL(y);
                }
        }

        // cross-lane reduce over the 4 row-groups (lanes l, l+16, l+32, l+48)
#pragma unroll
        for (int nf = 0; nf < 4; ++nf) {
            agg4[nf] += __shfl_xor(agg4[nf], 16);
            agg4[nf] += __shfl_xor(agg4[nf], 32);
        }
        if (l < 16) {
#pragma unroll
            for (int nf = 0; nf < 4; ++nf)
                AGG[nodei * 64 + nf * 16 + l] = agg4[nf];
        }
    }
}

// ---------------- Kernel 3: node MLP fn: [agg, x] -> 128 -> 128 -> 32 ----------------
// one block (128 threads) per node
__global__ __launch_bounds__(128) void k_fn(
    const float* __restrict__ AGG, const float* __restrict__ x,
    const float* __restrict__ W0, const float* __restrict__ b0,
    const float* __restrict__ W1, const float* __restrict__ b1,
    const float* __restrict__ W2, const float* __restrict__ b2,
    float* __restrict__ out)
{
    __shared__ float in96[96];
    __shared__ float h1[128];
    __shared__ float h2[128];
    const int node = blockIdx.x;
    const int t = threadIdx.x;
    if (t < 64) in96[t] = AGG[node * 64 + t];
    else if (t < 96) in96[t] = x[node * 32 + (t - 64)];
    __syncthreads();
    float a = b0[t];
#pragma unroll 4
    for (int k = 0; k < 96; ++k) a += in96[k] * W0[k * 128 + t];
    h1[t] = LREL(a);
    __syncthreads();
    a = b1[t];
#pragma unroll 4
    for (int k = 0; k < 128; ++k) a += h1[k] * W1[k * 128 + t];
    h2[t] = LREL(a);
    __syncthreads();
    if (t < 32) {
        a = b2[t];
#pragma unroll 4
        for (int k = 0; k < 128; ++k) a += h2[k] * W2[k * 32 + t];
        out[node * 32 + t] = a;
    }
}

extern "C" void kernel_launch(void* const* d_in, const int* in_sizes, int n_in,
                              void* d_out, int out_size, void* d_ws, size_t ws_size,
                              hipStream_t stream)
{
    const float* x    = (const float*)d_in[0];
    const float* feW0 = (const float*)d_in[1];
    const float* feb0 = (const float*)d_in[2];
    const float* feW1 = (const float*)d_in[3];
    const float* feb1 = (const float*)d_in[4];
    const float* feW2 = (const float*)d_in[5];
    const float* feb2 = (const float*)d_in[6];
    const float* fnW0 = (const float*)d_in[7];
    const float* fnb0 = (const float*)d_in[8];
    const float* fnW1 = (const float*)d_in[9];
    const float* fnb1 = (const float*)d_in[10];
    const float* fnW2 = (const float*)d_in[11];
    const float* fnb2 = (const float*)d_in[12];
    float* out = (float*)d_out;

    // workspace: U (1MB) | V (1MB) | AGG (1MB)  -- needs ws_size >= 3 MiB
    float* U   = (float*)d_ws;
    float* V   = U + 262144;
    float* AGG = V + 262144;

    hipLaunchKernelGGL(k_uv,   dim3(1024), dim3(256), 0, stream, x, feW0, feb0, U, V);
    hipLaunchKernelGGL(k_edge, dim3(512),  dim3(256), 0, stream, U, V, feW1, feb1, feW2, feb2, AGG);
    hipLaunchKernelGGL(k_fn,   dim3(4096), dim3(128), 0, stream, AGG, x, fnW0, fnb0, fnW1, fnb1, fnW2, fnb2, out);
}

// Round 2
// 102.700 us; speedup vs baseline: 1.0780x; 1.0780x over previous
//
#include <hip/hip_runtime.h>
#include <hip/hip_bf16.h>

#define ALPHA 0.2f
static __device__ __forceinline__ float lrel(float x) { return fmaxf(x, ALPHA * x); }

typedef __attribute__((ext_vector_type(8))) short bf16x8;
typedef __attribute__((ext_vector_type(4))) float f32x4;

union FragU { bf16x8 v; unsigned int u[4]; };

// pack two f32 -> one dword of 2 bf16 (RNE); compiler emits v_cvt_pk_bf16_f32
static __device__ __forceinline__ unsigned int pk2(float a, float b) {
    union { __hip_bfloat162 h; unsigned int u; } c;
    c.h = __float22bfloat162_rn(make_float2(a, b));
    return c.u;
}

// ---------------- Kernel 1: U = x @ W0[:32] + b0,  V = x @ W0[32:] ----------------
__global__ __launch_bounds__(256) void k_uv(
    const float* __restrict__ x, const float* __restrict__ W0, const float* __restrict__ b0,
    float* __restrict__ U, float* __restrict__ V)
{
    int idx = blockIdx.x * 256 + threadIdx.x;  // 0 .. 262143
    int n = idx >> 6;
    int k = idx & 63;
    const float* xr = x + n * 32;
    float u = b0[k], v = 0.f;
#pragma unroll
    for (int f = 0; f < 32; ++f) {
        float xv = xr[f];
        u += xv * W0[f * 64 + k];
        v += xv * W0[(32 + f) * 64 + k];
    }
    U[idx] = u;
    V[idx] = v;
}

// ---------------- Kernel 2: edge MLP (layers 1,2) + sum over j ----------------
// Transposed-GEMM scheme: D^T = W^T · h^T. Edge index lives on lane&15 for both
// GEMMs; W1's output features are permuted by pi(16nf+4a+r)=32(nf>>1)+8a+4(nf&1)+r
// so GEMM1's accumulator registers ARE GEMM2's B-fragment after lrelu+pack.
// grid: 1024 blocks (b 0..7 x ig 0..127), 256 threads = 4 waves, 1 node i per wave.
__global__ __launch_bounds__(256) void k_edge(
    const float* __restrict__ U, const float* __restrict__ V,
    const float* __restrict__ W1, const float* __restrict__ b1,
    const float* __restrict__ W2, const float* __restrict__ b2,
    float* __restrict__ AGG)
{
    const int tid = threadIdx.x;
    const int w = tid >> 6, l = tid & 63;
    const int lo = l & 15, g = l >> 4;
    const int bid = blockIdx.x;
    const int b = bid >> 7, ig = bid & 127;
    const int i = ig * 4 + w;
    const int node = b * 512 + i;

    // ---- weight fragments (A-operand = W^T rows): lane holds W[32s+8g+e][col]
    // W1 uses permuted column pc = pi(16nf+lo); W2 uses true column 16nf+lo.
    FragU w1f[2][4], w2f[2][4];
#pragma unroll
    for (int nf = 0; nf < 4; ++nf) {
        const int pc = 32 * (nf >> 1) + 8 * (lo >> 2) + 4 * (nf & 1) + (lo & 3);
        const int c2 = 16 * nf + lo;
#pragma unroll
        for (int s = 0; s < 2; ++s) {
#pragma unroll
            for (int uq = 0; uq < 4; ++uq) {
                const int k0 = 32 * s + 8 * g + 2 * uq;
                w1f[s][nf].u[uq] = pk2(W1[k0 * 64 + pc], W1[(k0 + 1) * 64 + pc]);
                w2f[s][nf].u[uq] = pk2(W2[k0 * 64 + c2], W2[(k0 + 1) * 64 + c2]);
            }
        }
    }
    // ---- bias vectors as MFMA C-init: b1 permuted, b2 true
    f32x4 b1f[4], b2f[4];
#pragma unroll
    for (int nf = 0; nf < 4; ++nf) {
        const float4 t1 = *(const float4*)(b1 + 32 * (nf >> 1) + 8 * g + 4 * (nf & 1));
        const float4 t2 = *(const float4*)(b2 + 16 * nf + 4 * g);
        b1f[nf] = (f32x4){t1.x, t1.y, t1.z, t1.w};
        b2f[nf] = (f32x4){t2.x, t2.y, t2.z, t2.w};
    }

    // ---- U fragment for node i: k = 32s + 8g + e
    const float* up = U + node * 64 + 8 * g;
    const float4 ua = *(const float4*)(up);
    const float4 ub = *(const float4*)(up + 4);
    const float4 uc = *(const float4*)(up + 32);
    const float4 ud = *(const float4*)(up + 36);

    const float* Vb = V + b * 512 * 64;
    // prefetch first V tile (edge = jc+lo)
    float4 va, vB, vc, vd;
    {
        const float* vp = Vb + lo * 64 + 8 * g;
        va = *(const float4*)(vp);
        vB = *(const float4*)(vp + 4);
        vc = *(const float4*)(vp + 32);
        vd = *(const float4*)(vp + 36);
    }

    f32x4 agg[4];
#pragma unroll
    for (int nf = 0; nf < 4; ++nf) { f32x4 z = {0.f, 0.f, 0.f, 0.f}; agg[nf] = z; }

#pragma unroll 1
    for (int jc = 0; jc < 512; jc += 16) {
        // prefetch next iteration's V
        const int jn = (jc + 16 < 512) ? jc + 16 : 0;
        const float* vp = Vb + (jn + lo) * 64 + 8 * g;
        const float4 nva = *(const float4*)(vp);
        const float4 nvb = *(const float4*)(vp + 4);
        const float4 nvc = *(const float4*)(vp + 32);
        const float4 nvd = *(const float4*)(vp + 36);

        // ---- h0 = lrelu(U_i + V_j), packed as B-fragment of h0^T
        FragU h0a, h0b;
        h0a.u[0] = pk2(lrel(ua.x + va.x), lrel(ua.y + va.y));
        h0a.u[1] = pk2(lrel(ua.z + va.z), lrel(ua.w + va.w));
        h0a.u[2] = pk2(lrel(ub.x + vB.x), lrel(ub.y + vB.y));
        h0a.u[3] = pk2(lrel(ub.z + vB.z), lrel(ub.w + vB.w));
        h0b.u[0] = pk2(lrel(uc.x + vc.x), lrel(uc.y + vc.y));
        h0b.u[1] = pk2(lrel(uc.z + vc.z), lrel(uc.w + vc.w));
        h0b.u[2] = pk2(lrel(ud.x + vd.x), lrel(ud.y + vd.y));
        h0b.u[3] = pk2(lrel(ud.z + vd.z), lrel(ud.w + vd.w));

        // ---- GEMM1: D1T = W1'^T @ h0^T  (bias folded into C-init)
        f32x4 acc1[4];
#pragma unroll
        for (int nf = 0; nf < 4; ++nf) {
            acc1[nf] = __builtin_amdgcn_mfma_f32_16x16x32_bf16(w1f[0][nf].v, h0a.v, b1f[nf], 0, 0, 0);
            acc1[nf] = __builtin_amdgcn_mfma_f32_16x16x32_bf16(w1f[1][nf].v, h0b.v, acc1[nf], 0, 0, 0);
        }

        // ---- lrelu + pack: registers line up as GEMM2's B-fragment (pi trick)
        FragU p0, p1;
        p0.u[0] = pk2(lrel(acc1[0][0]), lrel(acc1[0][1]));
        p0.u[1] = pk2(lrel(acc1[0][2]), lrel(acc1[0][3]));
        p0.u[2] = pk2(lrel(acc1[1][0]), lrel(acc1[1][1]));
        p0.u[3] = pk2(lrel(acc1[1][2]), lrel(acc1[1][3]));
        p1.u[0] = pk2(lrel(acc1[2][0]), lrel(acc1[2][1]));
        p1.u[1] = pk2(lrel(acc1[2][2]), lrel(acc1[2][3]));
        p1.u[2] = pk2(lrel(acc1[3][0]), lrel(acc1[3][1]));
        p1.u[3] = pk2(lrel(acc1[3][2]), lrel(acc1[3][3]));

        // ---- GEMM2: D2T = W2^T @ h1^T (bias folded into C-init)
        f32x4 acc2[4];
#pragma unroll
        for (int nf = 0; nf < 4; ++nf) {
            acc2[nf] = __builtin_amdgcn_mfma_f32_16x16x32_bf16(w2f[0][nf].v, p0.v, b2f[nf], 0, 0, 0);
            acc2[nf] = __builtin_amdgcn_mfma_f32_16x16x32_bf16(w2f[1][nf].v, p1.v, acc2[nf], 0, 0, 0);
        }

        // ---- sum over this lane's edge column
#pragma unroll
        for (int nf = 0; nf < 4; ++nf)
#pragma unroll
            for (int r = 0; r < 4; ++r) agg[nf][r] += lrel(acc2[nf][r]);

        va = nva; vB = nvb; vc = nvc; vd = nvd;
    }

    // ---- reduce over the 16 edge-lanes (lo), then lanes lo==0 hold full sums
#pragma unroll
    for (int nf = 0; nf < 4; ++nf)
#pragma unroll
        for (int r = 0; r < 4; ++r) {
            float v = agg[nf][r];
            v += __shfl_xor(v, 1);
            v += __shfl_xor(v, 2);
            v += __shfl_xor(v, 4);
            v += __shfl_xor(v, 8);
            agg[nf][r] = v;
        }
    if (lo == 0) {
#pragma unroll
        for (int nf = 0; nf < 4; ++nf) {
            float4 o = {agg[nf][0], agg[nf][1], agg[nf][2], agg[nf][3]};
            *(float4*)(AGG + node * 64 + 16 * nf + 4 * g) = o;
        }
    }
}

// ---------------- Kernel 3: node MLP fn: [agg, x] -> 128 -> 128 -> 32 ----------------
// 8 nodes per block (amortize weight re-reads), 256 threads.
__global__ __launch_bounds__(256) void k_fn(
    const float* __restrict__ AGG, const float* __restrict__ x,
    const float* __restrict__ W0, const float* __restrict__ b0,
    const float* __restrict__ W1, const float* __restrict__ b1,
    const float* __restrict__ W2, const float* __restrict__ b2,
    float* __restrict__ out)
{
    __shared__ float in96T[96][8];
    __shared__ float h1T[128][8];
    __shared__ float h2T[128][8];
    const int t = threadIdx.x;
    const int half = t >> 7, f = t & 127;
    const int node0 = blockIdx.x * 8;

    for (int idx = t; idx < 768; idx += 256) {
        int nn = idx & 7, k = idx >> 3;
        in96T[k][nn] = (k < 64) ? AGG[(node0 + nn) * 64 + k]
                                : x[(node0 + nn) * 32 + (k - 64)];
    }
    __syncthreads();

    // layer 1: 96 -> 128, 4 nodes per thread
    {
        float a0 = b0[f], a1 = a0, a2 = a0, a3 = a0;
#pragma unroll 4
        for (int k = 0; k < 96; ++k) {
            const float4 iv = *(const float4*)(&in96T[k][4 * half]);
            const float wv = W0[k * 128 + f];
            a0 += iv.x * wv; a1 += iv.y * wv; a2 += iv.z * wv; a3 += iv.w * wv;
        }
        float4 o = {lrel(a0), lrel(a1), lrel(a2), lrel(a3)};
        *(float4*)(&h1T[f][4 * half]) = o;
    }
    __syncthreads();

    // layer 2: 128 -> 128
    {
        float a0 = b1[f], a1 = a0, a2 = a0, a3 = a0;
#pragma unroll 4
        for (int k = 0; k < 128; ++k) {
            const float4 iv = *(const float4*)(&h1T[k][4 * half]);
            const float wv = W1[k * 128 + f];
            a0 += iv.x * wv; a1 += iv.y * wv; a2 += iv.z * wv; a3 += iv.w * wv;
        }
        float4 o = {lrel(a0), lrel(a1), lrel(a2), lrel(a3)};
        *(float4*)(&h2T[f][4 * half]) = o;
    }
    __syncthreads();

    // layer 3: 128 -> 32 (linear), one (node, feat) per thread
    {
        const int nn = t >> 5, fo = t & 31;
        float a = b2[fo];
#pragma unroll 4
        for (int k = 0; k < 128; ++k) a += h2T[k][nn] * W2[k * 32 + fo];
        out[(node0 + nn) * 32 + fo] = a;
    }
}

extern "C" void kernel_launch(void* const* d_in, const int* in_sizes, int n_in,
                              void* d_out, int out_size, void* d_ws, size_t ws_size,
                              hipStream_t stream)
{
    const float* x    = (const float*)d_in[0];
    const float* feW0 = (const float*)d_in[1];
    const float* feb0 = (const float*)d_in[2];
    const float* feW1 = (const float*)d_in[3];
    const float* feb1 = (const float*)d_in[4];
    const float* feW2 = (const float*)d_in[5];
    const float* feb2 = (const float*)d_in[6];
    const float* fnW0 = (const float*)d_in[7];
    const float* fnb0 = (const float*)d_in[8];
    const float* fnW1 = (const float*)d_in[9];
    const float* fnb1 = (const float*)d_in[10];
    const float* fnW2 = (const float*)d_in[11];
    const float* fnb2 = (const float*)d_in[12];
    float* out = (float*)d_out;

    // workspace: U (1MB) | V (1MB) | AGG (1MB)
    float* U   = (float*)d_ws;
    float* V   = U + 262144;
    float* AGG = V + 262144;

    hipLaunchKernelGGL(k_uv,   dim3(1024), dim3(256), 0, stream, x, feW0, feb0, U, V);
    hipLaunchKernelGGL(k_edge, dim3(1024), dim3(256), 0, stream, U, V, feW1, feb1, feW2, feb2, AGG);
    hipLaunchKernelGGL(k_fn,   dim3(512),  dim3(256), 0, stream, AGG, x, fnW0, fnb0, fnW1, fnb1, fnW2, fnb2, out);
}

// Round 3
// 102.305 us; speedup vs baseline: 1.0822x; 1.0039x over previous
//
#include <hip/hip_runtime.h>
#include <hip/hip_bf16.h>

#define ALPHA 0.2f
static __device__ __forceinline__ float lrel(float x) { return fmaxf(x, ALPHA * x); }

typedef __attribute__((ext_vector_type(8))) short bf16x8;
typedef __attribute__((ext_vector_type(4))) float f32x4;

union FragU { bf16x8 v; unsigned int u[4]; };

// pack two f32 -> one dword of 2 bf16 (RNE) via the HW instruction.
// (library __float22bfloat162_rn compiles to ~6-7 VALU ops w/ NaN checks)
static __device__ __forceinline__ unsigned int pk2(float a, float b) {
    unsigned int r;
    asm("v_cvt_pk_bf16_f32 %0, %1, %2" : "=v"(r) : "v"(a), "v"(b));
    return r;
}

// ---------------- Kernel 1: U = x @ W0[:32] + b0,  V = x @ W0[32:] ----------------
__global__ __launch_bounds__(256) void k_uv(
    const float* __restrict__ x, const float* __restrict__ W0, const float* __restrict__ b0,
    float* __restrict__ U, float* __restrict__ V)
{
    int idx = blockIdx.x * 256 + threadIdx.x;  // 0 .. 262143
    int n = idx >> 6;
    int k = idx & 63;
    const float* xr = x + n * 32;
    float u = b0[k], v = 0.f;
#pragma unroll
    for (int f = 0; f < 32; ++f) {
        float xv = xr[f];
        u += xv * W0[f * 64 + k];
        v += xv * W0[(32 + f) * 64 + k];
    }
    U[idx] = u;
    V[idx] = v;
}

// ---------------- Kernel 2: edge MLP (layers 1,2) + sum over j ----------------
// Transposed-GEMM scheme: D^T = W^T · h^T; edge index on lane&15 in both GEMMs.
// W1 column-permuted by pi(16nf+4a+r)=32(nf>>1)+8a+4(nf&1)+r so GEMM1's packed
// accumulators ARE GEMM2's B-fragment (zero repack).
// grid: 2048 blocks = 8(b) x 128(ig) x 2(j-half); 4 waves/block; 1 node i per wave,
// 256 j's per wave -> partial AGG per half, summed in k_fn.
__global__ __launch_bounds__(256) void k_edge(
    const float* __restrict__ U, const float* __restrict__ V,
    const float* __restrict__ W1, const float* __restrict__ b1,
    const float* __restrict__ W2, const float* __restrict__ b2,
    float* __restrict__ AGG)
{
    const int tid = threadIdx.x;
    const int w = tid >> 6, l = tid & 63;
    const int lo = l & 15, g = l >> 4;
    const int bid = blockIdx.x;
    const int b = bid >> 8, rem = bid & 255;
    const int ig = rem >> 1, half = rem & 1;
    const int i = ig * 4 + w;
    const int node = b * 512 + i;
    const int j0 = half * 256;

    // ---- weight fragments (A-operand = W^T rows): lane holds W[32s+8g+e][col]
    FragU w1f[2][4], w2f[2][4];
#pragma unroll
    for (int nf = 0; nf < 4; ++nf) {
        const int pc = 32 * (nf >> 1) + 8 * (lo >> 2) + 4 * (nf & 1) + (lo & 3);
        const int c2 = 16 * nf + lo;
#pragma unroll
        for (int s = 0; s < 2; ++s) {
#pragma unroll
            for (int uq = 0; uq < 4; ++uq) {
                const int k0 = 32 * s + 8 * g + 2 * uq;
                w1f[s][nf].u[uq] = pk2(W1[k0 * 64 + pc], W1[(k0 + 1) * 64 + pc]);
                w2f[s][nf].u[uq] = pk2(W2[k0 * 64 + c2], W2[(k0 + 1) * 64 + c2]);
            }
        }
    }
    // ---- bias vectors as MFMA C-init: b1 permuted, b2 true
    f32x4 b1f[4], b2f[4];
#pragma unroll
    for (int nf = 0; nf < 4; ++nf) {
        const float4 t1 = *(const float4*)(b1 + 32 * (nf >> 1) + 8 * g + 4 * (nf & 1));
        const float4 t2 = *(const float4*)(b2 + 16 * nf + 4 * g);
        b1f[nf] = (f32x4){t1.x, t1.y, t1.z, t1.w};
        b2f[nf] = (f32x4){t2.x, t2.y, t2.z, t2.w};
    }

    // ---- U fragment for node i: k = 32s + 8g + e
    const float* up = U + node * 64 + 8 * g;
    const float4 ua = *(const float4*)(up);
    const float4 ub = *(const float4*)(up + 4);
    const float4 uc = *(const float4*)(up + 32);
    const float4 ud = *(const float4*)(up + 36);

    const float* Vb = V + b * 512 * 64 + j0 * 64;
    // prefetch first V tile (edge = jc+lo)
    float4 va, vB, vc, vd;
    {
        const float* vp = Vb + lo * 64 + 8 * g;
        va = *(const float4*)(vp);
        vB = *(const float4*)(vp + 4);
        vc = *(const float4*)(vp + 32);
        vd = *(const float4*)(vp + 36);
    }

    f32x4 agg[4];
#pragma unroll
    for (int nf = 0; nf < 4; ++nf) { f32x4 z = {0.f, 0.f, 0.f, 0.f}; agg[nf] = z; }

#pragma unroll 1
    for (int jc = 0; jc < 256; jc += 16) {
        // prefetch next iteration's V
        const int jn = (jc + 16 < 256) ? jc + 16 : 0;
        const float* vp = Vb + (jn + lo) * 64 + 8 * g;
        const float4 nva = *(const float4*)(vp);
        const float4 nvb = *(const float4*)(vp + 4);
        const float4 nvc = *(const float4*)(vp + 32);
        const float4 nvd = *(const float4*)(vp + 36);

        // ---- h0 = lrelu(U_i + V_j), packed as B-fragment of h0^T
        FragU h0a, h0b;
        h0a.u[0] = pk2(lrel(ua.x + va.x), lrel(ua.y + va.y));
        h0a.u[1] = pk2(lrel(ua.z + va.z), lrel(ua.w + va.w));
        h0a.u[2] = pk2(lrel(ub.x + vB.x), lrel(ub.y + vB.y));
        h0a.u[3] = pk2(lrel(ub.z + vB.z), lrel(ub.w + vB.w));
        h0b.u[0] = pk2(lrel(uc.x + vc.x), lrel(uc.y + vc.y));
        h0b.u[1] = pk2(lrel(uc.z + vc.z), lrel(uc.w + vc.w));
        h0b.u[2] = pk2(lrel(ud.x + vd.x), lrel(ud.y + vd.y));
        h0b.u[3] = pk2(lrel(ud.z + vd.z), lrel(ud.w + vd.w));

        // ---- GEMM1: D1T = W1'^T @ h0^T (bias folded into C-init)
        f32x4 acc1[4];
#pragma unroll
        for (int nf = 0; nf < 4; ++nf) {
            acc1[nf] = __builtin_amdgcn_mfma_f32_16x16x32_bf16(w1f[0][nf].v, h0a.v, b1f[nf], 0, 0, 0);
            acc1[nf] = __builtin_amdgcn_mfma_f32_16x16x32_bf16(w1f[1][nf].v, h0b.v, acc1[nf], 0, 0, 0);
        }

        // ---- lrelu + pack: registers line up as GEMM2's B-fragment (pi trick)
        FragU p0, p1;
        p0.u[0] = pk2(lrel(acc1[0][0]), lrel(acc1[0][1]));
        p0.u[1] = pk2(lrel(acc1[0][2]), lrel(acc1[0][3]));
        p0.u[2] = pk2(lrel(acc1[1][0]), lrel(acc1[1][1]));
        p0.u[3] = pk2(lrel(acc1[1][2]), lrel(acc1[1][3]));
        p1.u[0] = pk2(lrel(acc1[2][0]), lrel(acc1[2][1]));
        p1.u[1] = pk2(lrel(acc1[2][2]), lrel(acc1[2][3]));
        p1.u[2] = pk2(lrel(acc1[3][0]), lrel(acc1[3][1]));
        p1.u[3] = pk2(lrel(acc1[3][2]), lrel(acc1[3][3]));

        // ---- GEMM2: D2T = W2^T @ h1^T (bias folded into C-init)
        f32x4 acc2[4];
#pragma unroll
        for (int nf = 0; nf < 4; ++nf) {
            acc2[nf] = __builtin_amdgcn_mfma_f32_16x16x32_bf16(w2f[0][nf].v, p0.v, b2f[nf], 0, 0, 0);
            acc2[nf] = __builtin_amdgcn_mfma_f32_16x16x32_bf16(w2f[1][nf].v, p1.v, acc2[nf], 0, 0, 0);
        }

        // ---- sum over this lane's edge column
#pragma unroll
        for (int nf = 0; nf < 4; ++nf)
#pragma unroll
            for (int r = 0; r < 4; ++r) agg[nf][r] += lrel(acc2[nf][r]);

        va = nva; vB = nvb; vc = nvc; vd = nvd;
    }

    // ---- reduce over the 16 edge-lanes (lo); lanes lo==0 hold full partial sums
#pragma unroll
    for (int nf = 0; nf < 4; ++nf)
#pragma unroll
        for (int r = 0; r < 4; ++r) {
            float v = agg[nf][r];
            v += __shfl_xor(v, 1);
            v += __shfl_xor(v, 2);
            v += __shfl_xor(v, 4);
            v += __shfl_xor(v, 8);
            agg[nf][r] = v;
        }
    if (lo == 0) {
#pragma unroll
        for (int nf = 0; nf < 4; ++nf) {
            float4 o = {agg[nf][0], agg[nf][1], agg[nf][2], agg[nf][3]};
            *(float4*)(AGG + half * 262144 + node * 64 + 16 * nf + 4 * g) = o;
        }
    }
}

// ---------------- Kernel 3: node MLP fn: [agg, x] -> 128 -> 128 -> 32 ----------------
// 8 nodes per block; sums the two AGG j-half partials on load.
__global__ __launch_bounds__(256) void k_fn(
    const float* __restrict__ AGG, const float* __restrict__ x,
    const float* __restrict__ W0, const float* __restrict__ b0,
    const float* __restrict__ W1, const float* __restrict__ b1,
    const float* __restrict__ W2, const float* __restrict__ b2,
    float* __restrict__ out)
{
    __shared__ float in96T[96][8];
    __shared__ float h1T[128][8];
    __shared__ float h2T[128][8];
    const int t = threadIdx.x;
    const int half = t >> 7, f = t & 127;
    const int node0 = blockIdx.x * 8;

    for (int idx = t; idx < 768; idx += 256) {
        int nn = idx & 7, k = idx >> 3;
        in96T[k][nn] = (k < 64)
            ? AGG[(node0 + nn) * 64 + k] + AGG[262144 + (node0 + nn) * 64 + k]
            : x[(node0 + nn) * 32 + (k - 64)];
    }
    __syncthreads();

    // layer 1: 96 -> 128, 4 nodes per thread
    {
        float a0 = b0[f], a1 = a0, a2 = a0, a3 = a0;
#pragma unroll 4
        for (int k = 0; k < 96; ++k) {
            const float4 iv = *(const float4*)(&in96T[k][4 * half]);
            const float wv = W0[k * 128 + f];
            a0 += iv.x * wv; a1 += iv.y * wv; a2 += iv.z * wv; a3 += iv.w * wv;
        }
        float4 o = {lrel(a0), lrel(a1), lrel(a2), lrel(a3)};
        *(float4*)(&h1T[f][4 * half]) = o;
    }
    __syncthreads();

    // layer 2: 128 -> 128
    {
        float a0 = b1[f], a1 = a0, a2 = a0, a3 = a0;
#pragma unroll 4
        for (int k = 0; k < 128; ++k) {
            const float4 iv = *(const float4*)(&h1T[k][4 * half]);
            const float wv = W1[k * 128 + f];
            a0 += iv.x * wv; a1 += iv.y * wv; a2 += iv.z * wv; a3 += iv.w * wv;
        }
        float4 o = {lrel(a0), lrel(a1), lrel(a2), lrel(a3)};
        *(float4*)(&h2T[f][4 * half]) = o;
    }
    __syncthreads();

    // layer 3: 128 -> 32 (linear)
    {
        const int nn = t >> 5, fo = t & 31;
        float a = b2[fo];
#pragma unroll 4
        for (int k = 0; k < 128; ++k) a += h2T[k][nn] * W2[k * 32 + fo];
        out[(node0 + nn) * 32 + fo] = a;
    }
}

extern "C" void kernel_launch(void* const* d_in, const int* in_sizes, int n_in,
                              void* d_out, int out_size, void* d_ws, size_t ws_size,
                              hipStream_t stream)
{
    const float* x    = (const float*)d_in[0];
    const float* feW0 = (const float*)d_in[1];
    const float* feb0 = (const float*)d_in[2];
    const float* feW1 = (const float*)d_in[3];
    const float* feb1 = (const float*)d_in[4];
    const float* feW2 = (const float*)d_in[5];
    const float* feb2 = (const float*)d_in[6];
    const float* fnW0 = (const float*)d_in[7];
    const float* fnb0 = (const float*)d_in[8];
    const float* fnW1 = (const float*)d_in[9];
    const float* fnb1 = (const float*)d_in[10];
    const float* fnW2 = (const float*)d_in[11];
    const float* fnb2 = (const float*)d_in[12];
    float* out = (float*)d_out;

    // workspace: U (1MB) | V (1MB) | AGG partials (2MB)
    float* U   = (float*)d_ws;
    float* V   = U + 262144;
    float* AGG = V + 262144;

    hipLaunchKernelGGL(k_uv,   dim3(1024), dim3(256), 0, stream, x, feW0, feb0, U, V);
    hipLaunchKernelGGL(k_edge, dim3(2048), dim3(256), 0, stream, U, V, feW1, feb1, feW2, feb2, AGG);
    hipLaunchKernelGGL(k_fn,   dim3(512),  dim3(256), 0, stream, AGG, x, fnW0, fnb0, fnW1, fnb1, fnW2, fnb2, out);
}

// Round 4
// 85.672 us; speedup vs baseline: 1.2922x; 1.1941x over previous
//
#include <hip/hip_runtime.h>
#include <hip/hip_bf16.h>

#define ALPHA 0.2f
static __device__ __forceinline__ float lrel(float x) { return fmaxf(x, ALPHA * x); }

typedef __attribute__((ext_vector_type(8))) short bf16x8;
typedef __attribute__((ext_vector_type(4))) float f32x4;

union FragU { bf16x8 v; unsigned int u[4]; uint4 q; };

// pack two f32 -> one dword of 2 bf16 (RNE) via the HW instruction
static __device__ __forceinline__ unsigned int pk2(float a, float b) {
    unsigned int r;
    asm("v_cvt_pk_bf16_f32 %0, %1, %2" : "=v"(r) : "v"(a), "v"(b));
    return r;
}

// ---------------- Kernel 1: U/V precompute + weight-fragment prep ----------------
// blocks 0..1023: U = x @ W0[:32] + b0, V = x @ W0[32:]
// block 1024: pack W1/W2 into per-lane MFMA fragment layout (16 frags x 64 lanes x 4 dw)
__global__ __launch_bounds__(256) void k_uv(
    const float* __restrict__ x, const float* __restrict__ W0, const float* __restrict__ b0,
    const float* __restrict__ W1, const float* __restrict__ W2,
    float* __restrict__ U, float* __restrict__ V, unsigned int* __restrict__ WF)
{
    if (blockIdx.x == 1024) {
        const int t = threadIdx.x;
        const int l = t & 63, part = t >> 6;       // 4 parts x 64 lanes
        const int lo = l & 15, g = l >> 4;
#pragma unroll
        for (int q = 0; q < 2; ++q) {
            const int ff = part * 2 + q;           // 0..7 = (s*4+nf)
            const int s = ff >> 2, nf = ff & 3;
            const int pc = 32 * (nf >> 1) + 8 * (lo >> 2) + 4 * (nf & 1) + (lo & 3);
            const int c2 = 16 * nf + lo;
            unsigned int o1[4], o2[4];
#pragma unroll
            for (int uq = 0; uq < 4; ++uq) {
                const int k0 = 32 * s + 8 * g + 2 * uq;
                o1[uq] = pk2(W1[k0 * 64 + pc], W1[(k0 + 1) * 64 + pc]);
                o2[uq] = pk2(W2[k0 * 64 + c2], W2[(k0 + 1) * 64 + c2]);
            }
            *(uint4*)(WF + (ff * 64 + l) * 4)       = make_uint4(o1[0], o1[1], o1[2], o1[3]);
            *(uint4*)(WF + ((8 + ff) * 64 + l) * 4) = make_uint4(o2[0], o2[1], o2[2], o2[3]);
        }
        return;
    }
    int idx = blockIdx.x * 256 + threadIdx.x;  // 0 .. 262143
    int n = idx >> 6;
    int k = idx & 63;
    const float* xr = x + n * 32;
    float u = b0[k], v = 0.f;
#pragma unroll
    for (int f = 0; f < 32; ++f) {
        float xv = xr[f];
        u += xv * W0[f * 64 + k];
        v += xv * W0[(32 + f) * 64 + k];
    }
    U[idx] = u;
    V[idx] = v;
}

// ---------------- Kernel 2: edge MLP (layers 1,2) + sum over j ----------------
// Transposed-GEMM scheme (edge on lane&15 in both GEMMs), pi-permuted W1 so GEMM1's
// packed accumulators ARE GEMM2's B-fragment. Dual independent j-tile chains per
// wave (jc and jc+16) + 256-VGPR budget (launch_bounds min 2 waves/EU) so the
// allocator can keep both chains' transients live instead of serializing.
__global__ __launch_bounds__(256, 2) void k_edge(
    const float* __restrict__ U, const float* __restrict__ V,
    const unsigned int* __restrict__ WF,
    const float* __restrict__ b1, const float* __restrict__ b2,
    float* __restrict__ AGG)
{
    const int tid = threadIdx.x;
    const int w = tid >> 6, l = tid & 63;
    const int lo = l & 15, g = l >> 4;
    const int bid = blockIdx.x;
    const int b = bid >> 7, ig = bid & 127;
    const int i = ig * 4 + w;
    const int node = b * 512 + i;

    // ---- weight fragments: 16 coalesced dwordx4 loads
    FragU w1f[2][4], w2f[2][4];
    const uint4* wp = (const uint4*)WF;
#pragma unroll
    for (int s = 0; s < 2; ++s)
#pragma unroll
        for (int nf = 0; nf < 4; ++nf) {
            w1f[s][nf].q = wp[(s * 4 + nf) * 64 + l];
            w2f[s][nf].q = wp[(8 + s * 4 + nf) * 64 + l];
        }

    // ---- bias vectors as MFMA C-init: b1 permuted, b2 true
    f32x4 b1f[4], b2f[4];
#pragma unroll
    for (int nf = 0; nf < 4; ++nf) {
        const float4 t1 = *(const float4*)(b1 + 32 * (nf >> 1) + 8 * g + 4 * (nf & 1));
        const float4 t2 = *(const float4*)(b2 + 16 * nf + 4 * g);
        b1f[nf] = (f32x4){t1.x, t1.y, t1.z, t1.w};
        b2f[nf] = (f32x4){t2.x, t2.y, t2.z, t2.w};
    }

    // ---- U fragment for node i: k = 32s + 8g + e
    const float* up = U + node * 64 + 8 * g;
    const float4 ua = *(const float4*)(up);
    const float4 ub = *(const float4*)(up + 4);
    const float4 uc = *(const float4*)(up + 32);
    const float4 ud = *(const float4*)(up + 36);

    const float* Vb = V + b * 512 * 64;
    // current V for chain A (rows jc+lo) and chain B (rows jc+16+lo)
    float4 vaA, vbA, vcA, vdA, vaB, vbB, vcB, vdB;
    {
        const float* pA = Vb + lo * 64 + 8 * g;
        vaA = *(const float4*)(pA);      vbA = *(const float4*)(pA + 4);
        vcA = *(const float4*)(pA + 32); vdA = *(const float4*)(pA + 36);
        const float* pB = Vb + (16 + lo) * 64 + 8 * g;
        vaB = *(const float4*)(pB);      vbB = *(const float4*)(pB + 4);
        vcB = *(const float4*)(pB + 32); vdB = *(const float4*)(pB + 36);
    }

    f32x4 agg[4];
#pragma unroll
    for (int nf = 0; nf < 4; ++nf) { f32x4 z = {0.f, 0.f, 0.f, 0.f}; agg[nf] = z; }

#pragma unroll 1
    for (int jc = 0; jc < 512; jc += 32) {
        // prefetch next iteration's V for both chains
        const int jn = (jc + 32 < 512) ? jc + 32 : 0;
        const float* pA = Vb + (jn + lo) * 64 + 8 * g;
        const float4 nvaA = *(const float4*)(pA);      const float4 nvbA = *(const float4*)(pA + 4);
        const float4 nvcA = *(const float4*)(pA + 32); const float4 nvdA = *(const float4*)(pA + 36);
        const float* pB = Vb + (jn + 16 + lo) * 64 + 8 * g;
        const float4 nvaB = *(const float4*)(pB);      const float4 nvbB = *(const float4*)(pB + 4);
        const float4 nvcB = *(const float4*)(pB + 32); const float4 nvdB = *(const float4*)(pB + 36);

        // ---- h0 = lrelu(U_i + V_j) for both chains
        FragU h0aA, h0bA, h0aB, h0bB;
        h0aA.u[0] = pk2(lrel(ua.x + vaA.x), lrel(ua.y + vaA.y));
        h0aA.u[1] = pk2(lrel(ua.z + vaA.z), lrel(ua.w + vaA.w));
        h0aA.u[2] = pk2(lrel(ub.x + vbA.x), lrel(ub.y + vbA.y));
        h0aA.u[3] = pk2(lrel(ub.z + vbA.z), lrel(ub.w + vbA.w));
        h0bA.u[0] = pk2(lrel(uc.x + vcA.x), lrel(uc.y + vcA.y));
        h0bA.u[1] = pk2(lrel(uc.z + vcA.z), lrel(uc.w + vcA.w));
        h0bA.u[2] = pk2(lrel(ud.x + vdA.x), lrel(ud.y + vdA.y));
        h0bA.u[3] = pk2(lrel(ud.z + vdA.z), lrel(ud.w + vdA.w));
        h0aB.u[0] = pk2(lrel(ua.x + vaB.x), lrel(ua.y + vaB.y));
        h0aB.u[1] = pk2(lrel(ua.z + vaB.z), lrel(ua.w + vaB.w));
        h0aB.u[2] = pk2(lrel(ub.x + vbB.x), lrel(ub.y + vbB.y));
        h0aB.u[3] = pk2(lrel(ub.z + vbB.z), lrel(ub.w + vbB.w));
        h0bB.u[0] = pk2(lrel(uc.x + vcB.x), lrel(uc.y + vcB.y));
        h0bB.u[1] = pk2(lrel(uc.z + vcB.z), lrel(uc.w + vcB.w));
        h0bB.u[2] = pk2(lrel(ud.x + vdB.x), lrel(ud.y + vdB.y));
        h0bB.u[3] = pk2(lrel(ud.z + vdB.z), lrel(ud.w + vdB.w));

        // ---- GEMM1 both chains (bias folded into C-init)
        f32x4 acc1A[4], acc1B[4];
#pragma unroll
        for (int nf = 0; nf < 4; ++nf) {
            acc1A[nf] = __builtin_amdgcn_mfma_f32_16x16x32_bf16(w1f[0][nf].v, h0aA.v, b1f[nf], 0, 0, 0);
            acc1B[nf] = __builtin_amdgcn_mfma_f32_16x16x32_bf16(w1f[0][nf].v, h0aB.v, b1f[nf], 0, 0, 0);
        }
#pragma unroll
        for (int nf = 0; nf < 4; ++nf) {
            acc1A[nf] = __builtin_amdgcn_mfma_f32_16x16x32_bf16(w1f[1][nf].v, h0bA.v, acc1A[nf], 0, 0, 0);
            acc1B[nf] = __builtin_amdgcn_mfma_f32_16x16x32_bf16(w1f[1][nf].v, h0bB.v, acc1B[nf], 0, 0, 0);
        }

        // ---- lrelu + pack (registers line up as GEMM2's B-fragment, pi trick)
        FragU p0A, p1A, p0B, p1B;
        p0A.u[0] = pk2(lrel(acc1A[0][0]), lrel(acc1A[0][1]));
        p0A.u[1] = pk2(lrel(acc1A[0][2]), lrel(acc1A[0][3]));
        p0A.u[2] = pk2(lrel(acc1A[1][0]), lrel(acc1A[1][1]));
        p0A.u[3] = pk2(lrel(acc1A[1][2]), lrel(acc1A[1][3]));
        p1A.u[0] = pk2(lrel(acc1A[2][0]), lrel(acc1A[2][1]));
        p1A.u[1] = pk2(lrel(acc1A[2][2]), lrel(acc1A[2][3]));
        p1A.u[2] = pk2(lrel(acc1A[3][0]), lrel(acc1A[3][1]));
        p1A.u[3] = pk2(lrel(acc1A[3][2]), lrel(acc1A[3][3]));
        p0B.u[0] = pk2(lrel(acc1B[0][0]), lrel(acc1B[0][1]));
        p0B.u[1] = pk2(lrel(acc1B[0][2]), lrel(acc1B[0][3]));
        p0B.u[2] = pk2(lrel(acc1B[1][0]), lrel(acc1B[1][1]));
        p0B.u[3] = pk2(lrel(acc1B[1][2]), lrel(acc1B[1][3]));
        p1B.u[0] = pk2(lrel(acc1B[2][0]), lrel(acc1B[2][1]));
        p1B.u[1] = pk2(lrel(acc1B[2][2]), lrel(acc1B[2][3]));
        p1B.u[2] = pk2(lrel(acc1B[3][0]), lrel(acc1B[3][1]));
        p1B.u[3] = pk2(lrel(acc1B[3][2]), lrel(acc1B[3][3]));

        // ---- GEMM2 both chains (bias folded into C-init)
        f32x4 acc2A[4], acc2B[4];
#pragma unroll
        for (int nf = 0; nf < 4; ++nf) {
            acc2A[nf] = __builtin_amdgcn_mfma_f32_16x16x32_bf16(w2f[0][nf].v, p0A.v, b2f[nf], 0, 0, 0);
            acc2B[nf] = __builtin_amdgcn_mfma_f32_16x16x32_bf16(w2f[0][nf].v, p0B.v, b2f[nf], 0, 0, 0);
        }
#pragma unroll
        for (int nf = 0; nf < 4; ++nf) {
            acc2A[nf] = __builtin_amdgcn_mfma_f32_16x16x32_bf16(w2f[1][nf].v, p1A.v, acc2A[nf], 0, 0, 0);
            acc2B[nf] = __builtin_amdgcn_mfma_f32_16x16x32_bf16(w2f[1][nf].v, p1B.v, acc2B[nf], 0, 0, 0);
        }

        // ---- lrelu + accumulate both chains
#pragma unroll
        for (int nf = 0; nf < 4; ++nf)
#pragma unroll
            for (int r = 0; r < 4; ++r)
                agg[nf][r] += lrel(acc2A[nf][r]) + lrel(acc2B[nf][r]);

        vaA = nvaA; vbA = nvbA; vcA = nvcA; vdA = nvdA;
        vaB = nvaB; vbB = nvbB; vcB = nvcB; vdB = nvdB;
    }

    // ---- reduce over the 16 edge-lanes (lo); lanes lo==0 hold full sums
#pragma unroll
    for (int nf = 0; nf < 4; ++nf)
#pragma unroll
        for (int r = 0; r < 4; ++r) {
            float v = agg[nf][r];
            v += __shfl_xor(v, 1);
            v += __shfl_xor(v, 2);
            v += __shfl_xor(v, 4);
            v += __shfl_xor(v, 8);
            agg[nf][r] = v;
        }
    if (lo == 0) {
#pragma unroll
        for (int nf = 0; nf < 4; ++nf) {
            float4 o = {agg[nf][0], agg[nf][1], agg[nf][2], agg[nf][3]};
            *(float4*)(AGG + node * 64 + 16 * nf + 4 * g) = o;
        }
    }
}

// ---------------- Kernel 3: node MLP fn: [agg, x] -> 128 -> 128 -> 32 ----------------
__global__ __launch_bounds__(256) void k_fn(
    const float* __restrict__ AGG, const float* __restrict__ x,
    const float* __restrict__ W0, const float* __restrict__ b0,
    const float* __restrict__ W1, const float* __restrict__ b1,
    const float* __restrict__ W2, const float* __restrict__ b2,
    float* __restrict__ out)
{
    __shared__ float in96T[96][8];
    __shared__ float h1T[128][8];
    __shared__ float h2T[128][8];
    const int t = threadIdx.x;
    const int half = t >> 7, f = t & 127;
    const int node0 = blockIdx.x * 8;

    for (int idx = t; idx < 768; idx += 256) {
        int nn = idx & 7, k = idx >> 3;
        in96T[k][nn] = (k < 64) ? AGG[(node0 + nn) * 64 + k]
                                : x[(node0 + nn) * 32 + (k - 64)];
    }
    __syncthreads();

    {
        float a0 = b0[f], a1 = a0, a2 = a0, a3 = a0;
#pragma unroll 4
        for (int k = 0; k < 96; ++k) {
            const float4 iv = *(const float4*)(&in96T[k][4 * half]);
            const float wv = W0[k * 128 + f];
            a0 += iv.x * wv; a1 += iv.y * wv; a2 += iv.z * wv; a3 += iv.w * wv;
        }
        float4 o = {lrel(a0), lrel(a1), lrel(a2), lrel(a3)};
        *(float4*)(&h1T[f][4 * half]) = o;
    }
    __syncthreads();

    {
        float a0 = b1[f], a1 = a0, a2 = a0, a3 = a0;
#pragma unroll 4
        for (int k = 0; k < 128; ++k) {
            const float4 iv = *(const float4*)(&h1T[k][4 * half]);
            const float wv = W1[k * 128 + f];
            a0 += iv.x * wv; a1 += iv.y * wv; a2 += iv.z * wv; a3 += iv.w * wv;
        }
        float4 o = {lrel(a0), lrel(a1), lrel(a2), lrel(a3)};
        *(float4*)(&h2T[f][4 * half]) = o;
    }
    __syncthreads();

    {
        const int nn = t >> 5, fo = t & 31;
        float a = b2[fo];
#pragma unroll 4
        for (int k = 0; k < 128; ++k) a += h2T[k][nn] * W2[k * 32 + fo];
        out[(node0 + nn) * 32 + fo] = a;
    }
}

extern "C" void kernel_launch(void* const* d_in, const int* in_sizes, int n_in,
                              void* d_out, int out_size, void* d_ws, size_t ws_size,
                              hipStream_t stream)
{
    const float* x    = (const float*)d_in[0];
    const float* feW0 = (const float*)d_in[1];
    const float* feb0 = (const float*)d_in[2];
    const float* feW1 = (const float*)d_in[3];
    const float* feb1 = (const float*)d_in[4];
    const float* feW2 = (const float*)d_in[5];
    const float* feb2 = (const float*)d_in[6];
    const float* fnW0 = (const float*)d_in[7];
    const float* fnb0 = (const float*)d_in[8];
    const float* fnW1 = (const float*)d_in[9];
    const float* fnb1 = (const float*)d_in[10];
    const float* fnW2 = (const float*)d_in[11];
    const float* fnb2 = (const float*)d_in[12];
    float* out = (float*)d_out;

    // workspace: U (1MB) | V (1MB) | AGG (1MB) | WF (16KB)
    float* U   = (float*)d_ws;
    float* V   = U + 262144;
    float* AGG = V + 262144;
    unsigned int* WF = (unsigned int*)(AGG + 262144);

    hipLaunchKernelGGL(k_uv,   dim3(1025), dim3(256), 0, stream, x, feW0, feb0, feW1, feW2, U, V, WF);
    hipLaunchKernelGGL(k_edge, dim3(1024), dim3(256), 0, stream, U, V, WF, feb1, feb2, AGG);
    hipLaunchKernelGGL(k_fn,   dim3(512),  dim3(256), 0, stream, AGG, x, fnW0, fnb0, fnW1, fnb1, fnW2, fnb2, out);
}